// Round 2
// baseline (643.963 us; speedup 1.0000x reference)
//
#include <hip/hip_runtime.h>

#define HID 128
#define C2 256   // HEADS*HID
#define NEG 0.2f

typedef __bf16 v8bf __attribute__((ext_vector_type(8)));
typedef float  v4f  __attribute__((ext_vector_type(4)));

__device__ __forceinline__ float bf2f(unsigned short u) {
    union { float f; unsigned int i; } v; v.i = ((unsigned int)u) << 16; return v.f;
}
__device__ __forceinline__ unsigned short f2bf(float f) {
    union { float f; unsigned int i; } v; v.f = f;
    unsigned int r = v.i + 0x7FFFu + ((v.i >> 16) & 1u);
    return (unsigned short)(r >> 16);
}
__device__ __forceinline__ float lrelu(float x) { return x > 0.f ? x : NEG * x; }

// ---------------- fp32 -> bf16 conversion (n divisible by 4) ----------------
__global__ __launch_bounds__(256) void cvt_bf16(const float* __restrict__ src,
                                                unsigned short* __restrict__ dst, int n) {
    int i = (blockIdx.x * 256 + threadIdx.x) * 4;
    if (i >= n) return;
    float4 v = *(const float4*)(src + i);
    ushort4 o;
    o.x = f2bf(v.x); o.y = f2bf(v.y); o.z = f2bf(v.z); o.w = f2bf(v.w);
    *(ushort4*)(dst + i) = o;
}

// ---------------- CSR build ----------------
__global__ void zero_int(int* p, int n) {
    int i = blockIdx.x * 256 + threadIdx.x;
    if (i < n) p[i] = 0;
}

__global__ void hist_kernel(const int* __restrict__ ei, int* __restrict__ cnt, int E, int N) {
    int i = blockIdx.x * 256 + threadIdx.x;
    if (i >= E + N) return;
    int d = (i < E) ? ei[E + i] : (i - E);   // row1 of edge_index = dst; self loops appended
    atomicAdd(&cnt[d], 1);
}

__global__ __launch_bounds__(256) void scanA(const int* __restrict__ cnt, int* __restrict__ rs,
                                             int* __restrict__ part, int N) {
    __shared__ int s[256];
    int t = threadIdx.x, i = blockIdx.x * 256 + t;
    int v = (i < N) ? cnt[i] : 0;
    s[t] = v; __syncthreads();
    for (int off = 1; off < 256; off <<= 1) {
        int x = (t >= off) ? s[t - off] : 0;
        __syncthreads();
        s[t] += x;
        __syncthreads();
    }
    if (i < N) rs[i] = s[t] - v;          // chunk-local exclusive scan
    if (t == 255) part[blockIdx.x] = s[255];
}

__global__ __launch_bounds__(256) void scanB(int* __restrict__ part, int n) {
    __shared__ int s[256];
    int t = threadIdx.x;
    int v = (t < n) ? part[t] : 0;
    s[t] = v; __syncthreads();
    for (int off = 1; off < 256; off <<= 1) {
        int x = (t >= off) ? s[t - off] : 0;
        __syncthreads();
        s[t] += x;
        __syncthreads();
    }
    if (t < n) part[t] = s[t] - v;        // exclusive scan of chunk totals
}

__global__ void scanC(int* __restrict__ rs, const int* __restrict__ part,
                      int* __restrict__ cur, int N, int ET) {
    int i = blockIdx.x * 256 + threadIdx.x;
    if (i < N) {
        int v = rs[i] + part[blockIdx.x];
        rs[i] = v;
        cur[i] = v;
    }
    if (i == 0) rs[N] = ET;
}

__global__ void scatter_kernel(const int* __restrict__ ei, int* __restrict__ cur,
                               int* __restrict__ csr, int E, int N) {
    int i = blockIdx.x * 256 + threadIdx.x;
    if (i >= E + N) return;
    int s, d;
    if (i < E) { s = ei[i]; d = ei[E + i]; } else { s = d = i - E; }
    int pos = atomicAdd(&cur[d], 1);
    csr[pos] = s;
}

// ---------------- GEMM: C[M,N] = A[M,K] @ B[K,N] (+bias fp32), A/B bf16, fp32 acc ----------------
// one wave per 16x16 C tile; mfma_f32_16x16x32_bf16
__global__ __launch_bounds__(256) void gemm16(const unsigned short* __restrict__ A,
                                              const unsigned short* __restrict__ B,
                                              const float* __restrict__ bias,
                                              unsigned short* __restrict__ C,
                                              int M, int N, int K) {
    int w = (blockIdx.x << 2) + (threadIdx.x >> 6);
    int ntiles = N >> 4;
    int mt = w / ntiles, nt = w - mt * ntiles;
    if (mt * 16 >= M) return;
    int lane = threadIdx.x & 63;
    int l16 = lane & 15, quad = lane >> 4;
    const unsigned short* Ap = A + (size_t)(mt * 16 + l16) * K + quad * 8;
    const unsigned short* Bp = B + (size_t)(quad * 8) * N + nt * 16 + l16;
    v4f acc = {0.f, 0.f, 0.f, 0.f};
    for (int k0 = 0; k0 < K; k0 += 32) {
        v8bf af = *(const v8bf*)(Ap + k0);
        v8bf bf;
        const unsigned short* bp = Bp + (size_t)k0 * N;
#pragma unroll
        for (int j = 0; j < 8; ++j) bf[j] = __builtin_bit_cast(__bf16, bp[(size_t)j * N]);
        acc = __builtin_amdgcn_mfma_f32_16x16x32_bf16(af, bf, acc, 0, 0, 0);
    }
    int col = nt * 16 + l16;
    float bv = bias ? bias[col] : 0.f;
    int row0 = mt * 16 + quad * 4;
#pragma unroll
    for (int r = 0; r < 4; ++r)
        C[(size_t)(row0 + r) * N + col] = f2bf(acc[r] + bv);
}

// ---------------- per-node attention dots: asd[n] = {as_h0, as_h1, ad_h0, ad_h1} ----------------
__global__ __launch_bounds__(256) void alpha_kernel(const unsigned short* __restrict__ h,
                                                    const float* __restrict__ asrc,
                                                    const float* __restrict__ adst,
                                                    float* __restrict__ asd) {
    int n = blockIdx.x;
    int t = threadIdx.x;                      // t = head*128 + c, matches a_src flat layout
    float v = bf2f(h[(size_t)n * C2 + t]);
    float sa = v * asrc[t];
    float sd = v * adst[t];
#pragma unroll
    for (int off = 32; off; off >>= 1) { sa += __shfl_xor(sa, off); sd += __shfl_xor(sd, off); }
    __shared__ float ls[8];
    if ((t & 63) == 0) { ls[t >> 6] = sa; ls[4 + (t >> 6)] = sd; }
    __syncthreads();
    if (t == 0) {
        asd[(size_t)n * 4 + 0] = ls[0] + ls[1];
        asd[(size_t)n * 4 + 1] = ls[2] + ls[3];
        asd[(size_t)n * 4 + 2] = ls[4] + ls[5];
        asd[(size_t)n * 4 + 3] = ls[6] + ls[7];
    }
}

// ---------------- per-destination softmax + aggregation; one wave per dest ----------------
__global__ __launch_bounds__(256) void agg_kernel(const int* __restrict__ rs,
                                                  const int* __restrict__ csr,
                                                  const unsigned short* __restrict__ h,
                                                  const float* __restrict__ asd,
                                                  const float* __restrict__ bias,
                                                  unsigned short* __restrict__ out, int N) {
    int d = blockIdx.x * 4 + (threadIdx.x >> 6);
    if (d >= N) return;
    int lane = threadIdx.x & 63;
    int beg = rs[d], end = rs[d + 1];
    float ad0 = asd[(size_t)d * 4 + 2], ad1 = asd[(size_t)d * 4 + 3];

    // phase 1: segment max per head
    float m0 = -1e30f, m1 = -1e30f;
    for (int i = beg + lane; i < end; i += 64) {
        int s = csr[i];
        float e0 = lrelu(asd[(size_t)s * 4 + 0] + ad0);
        float e1 = lrelu(asd[(size_t)s * 4 + 1] + ad1);
        m0 = fmaxf(m0, e0); m1 = fmaxf(m1, e1);
    }
#pragma unroll
    for (int off = 32; off; off >>= 1) {
        m0 = fmaxf(m0, __shfl_xor(m0, off));
        m1 = fmaxf(m1, __shfl_xor(m1, off));
    }
    // phase 2: exp-sum per head
    float s0 = 0.f, s1 = 0.f;
    for (int i = beg + lane; i < end; i += 64) {
        int s = csr[i];
        float e0 = lrelu(asd[(size_t)s * 4 + 0] + ad0);
        float e1 = lrelu(asd[(size_t)s * 4 + 1] + ad1);
        s0 += expf(e0 - m0); s1 += expf(e1 - m1);
    }
#pragma unroll
    for (int off = 32; off; off >>= 1) { s0 += __shfl_xor(s0, off); s1 += __shfl_xor(s1, off); }
    float r0 = 1.f / (s0 + 1e-16f), r1 = 1.f / (s1 + 1e-16f);

    // phase 3: weighted gather; lane covers channels [lane*4, lane*4+4)
    int head = lane >> 5;
    float mh = head ? m1 : m0, rh = head ? r1 : r0, adh = head ? ad1 : ad0;
    int cbase = lane * 4;
    float a0 = 0.f, a1 = 0.f, a2 = 0.f, a3 = 0.f;
    for (int i = beg; i < end; ++i) {
        int s = csr[i];
        float e = lrelu(asd[(size_t)s * 4 + head] + adh);
        float wgt = expf(e - mh) * rh;
        ushort4 hv = *(const ushort4*)(h + (size_t)s * C2 + cbase);
        a0 += wgt * bf2f(hv.x); a1 += wgt * bf2f(hv.y);
        a2 += wgt * bf2f(hv.z); a3 += wgt * bf2f(hv.w);
    }
    ushort4 o;
    o.x = f2bf(fmaxf(a0 + bias[cbase + 0], 0.f));
    o.y = f2bf(fmaxf(a1 + bias[cbase + 1], 0.f));
    o.z = f2bf(fmaxf(a2 + bias[cbase + 2], 0.f));
    o.w = f2bf(fmaxf(a3 + bias[cbase + 3], 0.f));
    *(ushort4*)(out + (size_t)d * C2 + cbase) = o;
}

// ---------------- final: out[n] = sigmoid(t[n,0:128] . Wp2 + bp2), fp32 out ----------------
__global__ __launch_bounds__(256) void final_kernel(const unsigned short* __restrict__ t128,
                                                    const float* __restrict__ wp2,
                                                    const float* __restrict__ bp2,
                                                    float* __restrict__ out, int N) {
    int n = blockIdx.x * 4 + (threadIdx.x >> 6);
    if (n >= N) return;
    int lane = threadIdx.x & 63;
    float v = bf2f(t128[(size_t)n * 128 + lane]) * wp2[lane]
            + bf2f(t128[(size_t)n * 128 + 64 + lane]) * wp2[64 + lane];
#pragma unroll
    for (int off = 32; off; off >>= 1) v += __shfl_xor(v, off);
    if (lane == 0) {
        float x = v + bp2[0];
        out[n] = 1.f / (1.f + expf(-x));
    }
}

extern "C" void kernel_launch(void* const* d_in, const int* in_sizes, int n_in,
                              void* d_out, int out_size, void* d_ws, size_t ws_size,
                              hipStream_t stream) {
    const float* x   = (const float*)d_in[0];
    const int*   ei  = (const int*)d_in[1];
    const float* W1  = (const float*)d_in[2];
    const float* as1 = (const float*)d_in[3];
    const float* ad1 = (const float*)d_in[4];
    const float* b1  = (const float*)d_in[5];
    const float* W2  = (const float*)d_in[6];
    const float* as2 = (const float*)d_in[7];
    const float* ad2 = (const float*)d_in[8];
    const float* b2  = (const float*)d_in[9];
    const float* Wp1 = (const float*)d_in[10];
    const float* bp1 = (const float*)d_in[11];
    const float* Wp2 = (const float*)d_in[12];
    const float* bp2 = (const float*)d_in[13];
    float* out = (float*)d_out;

    int NN = in_sizes[0] / HID;   // 50000
    int E  = in_sizes[1] / 2;     // 800000
    int ET = E + NN;              // + self loops

    char* ws = (char*)d_ws;
    size_t off = 0;
    auto alloc = [&](size_t bytes) -> char* {
        char* p = ws + off;
        off += (bytes + 255) & ~(size_t)255;
        return p;
    };
    unsigned short* bufH = (unsigned short*)alloc((size_t)NN * C2 * 2);  // h (layer in-flight)
    unsigned short* bufO = (unsigned short*)alloc((size_t)NN * C2 * 2);  // relu(agg) output
    float* asd = (float*)alloc((size_t)NN * 4 * sizeof(float));
    int* rs    = (int*)alloc((size_t)(NN + 1) * 4);
    int* cur   = (int*)alloc((size_t)NN * 4);   // doubles as counts
    int* csr   = (int*)alloc((size_t)ET * 4);
    int* part  = (int*)alloc(1024);
    unsigned short* W1b  = (unsigned short*)alloc((size_t)HID * C2 * 2);
    unsigned short* W2b  = (unsigned short*)alloc((size_t)C2 * C2 * 2);
    unsigned short* Wp1b = (unsigned short*)alloc((size_t)C2 * HID * 2);
    // x in bf16: aliases bufO (x is dead before agg1 writes bufO)
    unsigned short* xb = bufO;

    int nchunk = (NN + 255) / 256;
    int eblk   = (ET + 255) / 256;
    auto cvt = [&](const float* s, unsigned short* d, int n) {
        cvt_bf16<<<(n / 4 + 255) / 256, 256, 0, stream>>>(s, d, n);
    };

    // dtype staging
    cvt(x,   xb,   NN * HID);
    cvt(W1,  W1b,  HID * C2);
    cvt(W2,  W2b,  C2 * C2);
    cvt(Wp1, Wp1b, C2 * HID);

    // CSR build (sort edges by destination)
    zero_int<<<nchunk, 256, 0, stream>>>(cur, NN);
    hist_kernel<<<eblk, 256, 0, stream>>>(ei, cur, E, NN);
    scanA<<<nchunk, 256, 0, stream>>>(cur, rs, part, NN);
    scanB<<<1, 256, 0, stream>>>(part, nchunk);
    scanC<<<nchunk, 256, 0, stream>>>(rs, part, cur, NN, ET);
    scatter_kernel<<<eblk, 256, 0, stream>>>(ei, cur, csr, E, NN);

    int waves256 = (NN / 16) * (C2 / 16);
    int waves128 = (NN / 16) * (HID / 16);

    // layer 1
    gemm16<<<(waves256 + 3) / 4, 256, 0, stream>>>(xb, W1b, nullptr, bufH, NN, C2, HID);
    alpha_kernel<<<NN, 256, 0, stream>>>(bufH, as1, ad1, asd);
    agg_kernel<<<(NN + 3) / 4, 256, 0, stream>>>(rs, csr, bufH, asd, b1, bufO, NN);
    // layer 2
    gemm16<<<(waves256 + 3) / 4, 256, 0, stream>>>(bufO, W2b, nullptr, bufH, NN, C2, C2);
    alpha_kernel<<<NN, 256, 0, stream>>>(bufH, as2, ad2, asd);
    agg_kernel<<<(NN + 3) / 4, 256, 0, stream>>>(rs, csr, bufH, asd, b2, bufO, NN);
    // post-MLP
    gemm16<<<(waves128 + 3) / 4, 256, 0, stream>>>(bufO, Wp1b, bp1, bufH, NN, HID, C2);
    final_kernel<<<(NN + 3) / 4, 256, 0, stream>>>(bufH, Wp2, bp2, out, NN);
}

// Round 3
// 537.836 us; speedup vs baseline: 1.1973x; 1.1973x over previous
//
#include <hip/hip_runtime.h>

#define HID 128
#define C2 256   // HEADS*HID
#define NEG 0.2f

typedef __bf16 v8bf __attribute__((ext_vector_type(8)));
typedef float  v4f  __attribute__((ext_vector_type(4)));
typedef unsigned short us8 __attribute__((ext_vector_type(8)));

__device__ __forceinline__ float bf2f(unsigned short u) {
    union { float f; unsigned int i; } v; v.i = ((unsigned int)u) << 16; return v.f;
}
__device__ __forceinline__ unsigned short f2bf(float f) {
    union { float f; unsigned int i; } v; v.f = f;
    unsigned int r = v.i + 0x7FFFu + ((v.i >> 16) & 1u);
    return (unsigned short)(r >> 16);
}
__device__ __forceinline__ float lrelu(float x) { return x > 0.f ? x : NEG * x; }

// ---------------- fp32 -> bf16 conversion (n divisible by 4) ----------------
__global__ __launch_bounds__(256) void cvt_bf16(const float* __restrict__ src,
                                                unsigned short* __restrict__ dst, int n) {
    int i = (blockIdx.x * 256 + threadIdx.x) * 4;
    if (i >= n) return;
    float4 v = *(const float4*)(src + i);
    ushort4 o;
    o.x = f2bf(v.x); o.y = f2bf(v.y); o.z = f2bf(v.z); o.w = f2bf(v.w);
    *(ushort4*)(dst + i) = o;
}

// ---------------- fp32 W[K,N] -> bf16 Wt[N,K] transpose staging ----------------
__global__ __launch_bounds__(256) void cvtT_bf16(const float* __restrict__ src,
                                                 unsigned short* __restrict__ dst,
                                                 int K, int N) {
    int i = blockIdx.x * 256 + threadIdx.x;
    if (i >= K * N) return;
    int k = i / N, n = i - k * N;
    dst[(size_t)n * K + k] = f2bf(src[i]);
}

// ---------------- CSR build ----------------
__global__ void zero_int(int* p, int n) {
    int i = blockIdx.x * 256 + threadIdx.x;
    if (i < n) p[i] = 0;
}

__global__ void hist_kernel(const int* __restrict__ ei, int* __restrict__ cnt, int E, int N) {
    int i = blockIdx.x * 256 + threadIdx.x;
    if (i >= E + N) return;
    int d = (i < E) ? ei[E + i] : (i - E);
    atomicAdd(&cnt[d], 1);
}

__global__ __launch_bounds__(256) void scanA(const int* __restrict__ cnt, int* __restrict__ rs,
                                             int* __restrict__ part, int N) {
    __shared__ int s[256];
    int t = threadIdx.x, i = blockIdx.x * 256 + t;
    int v = (i < N) ? cnt[i] : 0;
    s[t] = v; __syncthreads();
    for (int off = 1; off < 256; off <<= 1) {
        int x = (t >= off) ? s[t - off] : 0;
        __syncthreads();
        s[t] += x;
        __syncthreads();
    }
    if (i < N) rs[i] = s[t] - v;
    if (t == 255) part[blockIdx.x] = s[255];
}

__global__ __launch_bounds__(256) void scanB(int* __restrict__ part, int n) {
    __shared__ int s[256];
    int t = threadIdx.x;
    int v = (t < n) ? part[t] : 0;
    s[t] = v; __syncthreads();
    for (int off = 1; off < 256; off <<= 1) {
        int x = (t >= off) ? s[t - off] : 0;
        __syncthreads();
        s[t] += x;
        __syncthreads();
    }
    if (t < n) part[t] = s[t] - v;
}

__global__ void scanC(int* __restrict__ rs, const int* __restrict__ part,
                      int* __restrict__ cur, int N, int ET) {
    int i = blockIdx.x * 256 + threadIdx.x;
    if (i < N) {
        int v = rs[i] + part[blockIdx.x];
        rs[i] = v;
        cur[i] = v;
    }
    if (i == 0) rs[N] = ET;
}

__global__ void scatter_kernel(const int* __restrict__ ei, int* __restrict__ cur,
                               int* __restrict__ csr, int E, int N) {
    int i = blockIdx.x * 256 + threadIdx.x;
    if (i >= E + N) return;
    int s, d;
    if (i < E) { s = ei[i]; d = ei[E + i]; } else { s = d = i - E; }
    int pos = atomicAdd(&cur[d], 1);
    csr[pos] = s;
}

// ---------------- GEMM: C[M,N] = A[M,K] @ Bt[N,K]^T (+bias fp32) ----------------
// one wave computes a 16x128 strip (8 n-tiles); A-fragment reused 8x.
// mfma layout: A[m=l16][k=quad*8+j], B[k=quad*8+j][n=l16], D col=l16,row=quad*4+r
__global__ __launch_bounds__(256) void gemm_row(const unsigned short* __restrict__ A,
                                                const unsigned short* __restrict__ Bt,
                                                const float* __restrict__ bias,
                                                unsigned short* __restrict__ C,
                                                int M, int N, int K) {
    int ngrp = N >> 7;                       // groups of 128 cols
    int w = (blockIdx.x << 2) + (threadIdx.x >> 6);
    int mt = w / ngrp, g = w - mt * ngrp;
    if (mt * 16 >= M) return;
    int lane = threadIdx.x & 63;
    int l16 = lane & 15, quad = lane >> 4;
    int n0 = g << 7;
    const unsigned short* Ap  = A  + (size_t)(mt * 16 + l16) * K + quad * 8;
    const unsigned short* Bp  = Bt + (size_t)(n0 + l16) * K + quad * 8;
    v4f acc[8];
#pragma unroll
    for (int t = 0; t < 8; ++t) acc[t] = (v4f){0.f, 0.f, 0.f, 0.f};
    for (int k0 = 0; k0 < K; k0 += 32) {
        v8bf af = *(const v8bf*)(Ap + k0);
#pragma unroll
        for (int t = 0; t < 8; ++t) {
            v8bf bfr = *(const v8bf*)(Bp + (size_t)t * 16 * K + k0);
            acc[t] = __builtin_amdgcn_mfma_f32_16x16x32_bf16(af, bfr, acc[t], 0, 0, 0);
        }
    }
    int row0 = mt * 16 + quad * 4;
#pragma unroll
    for (int t = 0; t < 8; ++t) {
        int col = n0 + t * 16 + l16;
        float bv = bias ? bias[col] : 0.f;
#pragma unroll
        for (int r = 0; r < 4; ++r)
            C[(size_t)(row0 + r) * N + col] = f2bf(acc[t][r] + bv);
    }
}

// ---------------- per-node attention dots: asd[n] = {as_h0, as_h1, ad_h0, ad_h1} ----------------
__global__ __launch_bounds__(256) void alpha_kernel(const unsigned short* __restrict__ h,
                                                    const float* __restrict__ asrc,
                                                    const float* __restrict__ adst,
                                                    float* __restrict__ asd) {
    int n = blockIdx.x;
    int t = threadIdx.x;
    float v = bf2f(h[(size_t)n * C2 + t]);
    float sa = v * asrc[t];
    float sd = v * adst[t];
#pragma unroll
    for (int off = 32; off; off >>= 1) { sa += __shfl_xor(sa, off); sd += __shfl_xor(sd, off); }
    __shared__ float ls[8];
    if ((t & 63) == 0) { ls[t >> 6] = sa; ls[4 + (t >> 6)] = sd; }
    __syncthreads();
    if (t == 0) {
        asd[(size_t)n * 4 + 0] = ls[0] + ls[1];
        asd[(size_t)n * 4 + 1] = ls[2] + ls[3];
        asd[(size_t)n * 4 + 2] = ls[4] + ls[5];
        asd[(size_t)n * 4 + 3] = ls[6] + ls[7];
    }
}

// ---------------- per-destination softmax + aggregation; one wave per dest ----------------
// phase 3: 2 edges per iteration, 16B/lane; lane = e2*32 + sub, sub covers 8 channels.
__global__ __launch_bounds__(256) void agg_kernel(const int* __restrict__ rs,
                                                  const int* __restrict__ csr,
                                                  const unsigned short* __restrict__ h,
                                                  const float* __restrict__ asd,
                                                  const float* __restrict__ bias,
                                                  unsigned short* __restrict__ out, int N) {
    int d = blockIdx.x * 4 + (threadIdx.x >> 6);
    if (d >= N) return;
    int lane = threadIdx.x & 63;
    int beg = rs[d], end = rs[d + 1];
    float ad0 = asd[(size_t)d * 4 + 2], ad1 = asd[(size_t)d * 4 + 3];

    // phase 1: segment max per head (lanes over edges)
    float m0 = -1e30f, m1 = -1e30f;
    for (int i = beg + lane; i < end; i += 64) {
        int s = csr[i];
        float e0 = lrelu(asd[(size_t)s * 4 + 0] + ad0);
        float e1 = lrelu(asd[(size_t)s * 4 + 1] + ad1);
        m0 = fmaxf(m0, e0); m1 = fmaxf(m1, e1);
    }
#pragma unroll
    for (int off = 32; off; off >>= 1) {
        m0 = fmaxf(m0, __shfl_xor(m0, off));
        m1 = fmaxf(m1, __shfl_xor(m1, off));
    }
    // phase 2: exp-sum per head
    float s0 = 0.f, s1 = 0.f;
    for (int i = beg + lane; i < end; i += 64) {
        int s = csr[i];
        float e0 = lrelu(asd[(size_t)s * 4 + 0] + ad0);
        float e1 = lrelu(asd[(size_t)s * 4 + 1] + ad1);
        s0 += expf(e0 - m0); s1 += expf(e1 - m1);
    }
#pragma unroll
    for (int off = 32; off; off >>= 1) { s0 += __shfl_xor(s0, off); s1 += __shfl_xor(s1, off); }
    float r0 = 1.f / (s0 + 1e-16f), r1 = 1.f / (s1 + 1e-16f);

    // phase 3: weighted gather, 2 edges/iter, 16B/lane
    int e2 = lane >> 5;          // which edge of the pair
    int sub = lane & 31;         // channel group: 8 ch each
    int head = sub >> 4;
    float mh = head ? m1 : m0, rh = head ? r1 : r0, adh = head ? ad1 : ad0;
    int cbase = sub * 8;
    float a[8];
#pragma unroll
    for (int j = 0; j < 8; ++j) a[j] = 0.f;
#pragma unroll 2
    for (int i = beg; i < end; i += 2) {
        int ei = i + e2;
        bool valid = ei < end;
        int s = csr[valid ? ei : end - 1];
        float e = lrelu(asd[(size_t)s * 4 + head] + adh);
        float wgt = valid ? expf(e - mh) * rh : 0.f;
        us8 hv = *(const us8*)(h + (size_t)s * C2 + cbase);
#pragma unroll
        for (int j = 0; j < 8; ++j) a[j] += wgt * bf2f(hv[j]);
    }
#pragma unroll
    for (int j = 0; j < 8; ++j) a[j] += __shfl_xor(a[j], 32);
    if (e2 == 0) {
        us8 o;
#pragma unroll
        for (int j = 0; j < 8; ++j) o[j] = f2bf(fmaxf(a[j] + bias[cbase + j], 0.f));
        *(us8*)(out + (size_t)d * C2 + cbase) = o;
    }
}

// ---------------- final: out[n] = sigmoid(t[n,0:128] . Wp2 + bp2), fp32 out ----------------
__global__ __launch_bounds__(256) void final_kernel(const unsigned short* __restrict__ t128,
                                                    const float* __restrict__ wp2,
                                                    const float* __restrict__ bp2,
                                                    float* __restrict__ out, int N) {
    int n = blockIdx.x * 4 + (threadIdx.x >> 6);
    if (n >= N) return;
    int lane = threadIdx.x & 63;
    float v = bf2f(t128[(size_t)n * 128 + lane]) * wp2[lane]
            + bf2f(t128[(size_t)n * 128 + 64 + lane]) * wp2[64 + lane];
#pragma unroll
    for (int off = 32; off; off >>= 1) v += __shfl_xor(v, off);
    if (lane == 0) {
        float x = v + bp2[0];
        out[n] = 1.f / (1.f + expf(-x));
    }
}

extern "C" void kernel_launch(void* const* d_in, const int* in_sizes, int n_in,
                              void* d_out, int out_size, void* d_ws, size_t ws_size,
                              hipStream_t stream) {
    const float* x   = (const float*)d_in[0];
    const int*   ei  = (const int*)d_in[1];
    const float* W1  = (const float*)d_in[2];
    const float* as1 = (const float*)d_in[3];
    const float* ad1 = (const float*)d_in[4];
    const float* b1  = (const float*)d_in[5];
    const float* W2  = (const float*)d_in[6];
    const float* as2 = (const float*)d_in[7];
    const float* ad2 = (const float*)d_in[8];
    const float* b2  = (const float*)d_in[9];
    const float* Wp1 = (const float*)d_in[10];
    const float* bp1 = (const float*)d_in[11];
    const float* Wp2 = (const float*)d_in[12];
    const float* bp2 = (const float*)d_in[13];
    float* out = (float*)d_out;

    int NN = in_sizes[0] / HID;   // 50000
    int E  = in_sizes[1] / 2;     // 800000
    int ET = E + NN;

    char* ws = (char*)d_ws;
    size_t off = 0;
    auto alloc = [&](size_t bytes) -> char* {
        char* p = ws + off;
        off += (bytes + 255) & ~(size_t)255;
        return p;
    };
    unsigned short* bufH = (unsigned short*)alloc((size_t)NN * C2 * 2);
    unsigned short* bufO = (unsigned short*)alloc((size_t)NN * C2 * 2);
    float* asd = (float*)alloc((size_t)NN * 4 * sizeof(float));
    int* rs    = (int*)alloc((size_t)(NN + 1) * 4);
    int* cur   = (int*)alloc((size_t)NN * 4);
    int* csr   = (int*)alloc((size_t)ET * 4);
    int* part  = (int*)alloc(1024);
    unsigned short* W1t  = (unsigned short*)alloc((size_t)HID * C2 * 2);  // [256,128]
    unsigned short* W2t  = (unsigned short*)alloc((size_t)C2 * C2 * 2);   // [256,256]
    unsigned short* Wp1t = (unsigned short*)alloc((size_t)C2 * HID * 2);  // [128,256]
    unsigned short* xb = bufO;    // x-bf16 aliases bufO (dead before agg1 writes it)

    int nchunk = (NN + 255) / 256;
    int eblk   = (ET + 255) / 256;

    // dtype staging
    cvt_bf16<<<(NN * HID / 4 + 255) / 256, 256, 0, stream>>>(x, xb, NN * HID);
    cvtT_bf16<<<(HID * C2 + 255) / 256, 256, 0, stream>>>(W1, W1t, HID, C2);
    cvtT_bf16<<<(C2 * C2 + 255) / 256, 256, 0, stream>>>(W2, W2t, C2, C2);
    cvtT_bf16<<<(C2 * HID + 255) / 256, 256, 0, stream>>>(Wp1, Wp1t, C2, HID);

    // CSR build
    zero_int<<<nchunk, 256, 0, stream>>>(cur, NN);
    hist_kernel<<<eblk, 256, 0, stream>>>(ei, cur, E, NN);
    scanA<<<nchunk, 256, 0, stream>>>(cur, rs, part, NN);
    scanB<<<1, 256, 0, stream>>>(part, nchunk);
    scanC<<<nchunk, 256, 0, stream>>>(rs, part, cur, NN, ET);
    scatter_kernel<<<eblk, 256, 0, stream>>>(ei, cur, csr, E, NN);

    int mt = NN / 16;                       // 3125 m-tiles
    int w256 = mt * (C2 / 128);             // 16x128 strips, N=256
    int w128 = mt * (HID / 128);            // N=128

    // layer 1
    gemm_row<<<(w256 + 3) / 4, 256, 0, stream>>>(xb, W1t, nullptr, bufH, NN, C2, HID);
    alpha_kernel<<<NN, 256, 0, stream>>>(bufH, as1, ad1, asd);
    agg_kernel<<<(NN + 3) / 4, 256, 0, stream>>>(rs, csr, bufH, asd, b1, bufO, NN);
    // layer 2
    gemm_row<<<(w256 + 3) / 4, 256, 0, stream>>>(bufO, W2t, nullptr, bufH, NN, C2, C2);
    alpha_kernel<<<NN, 256, 0, stream>>>(bufH, as2, ad2, asd);
    agg_kernel<<<(NN + 3) / 4, 256, 0, stream>>>(rs, csr, bufH, asd, b2, bufO, NN);
    // post-MLP
    gemm_row<<<(w128 + 3) / 4, 256, 0, stream>>>(bufO, Wp1t, bp1, bufH, NN, HID, C2);
    final_kernel<<<(NN + 3) / 4, 256, 0, stream>>>(bufH, Wp2, bp2, out, NN);
}

// Round 4
// 450.463 us; speedup vs baseline: 1.4296x; 1.1940x over previous
//
#include <hip/hip_runtime.h>

#define HID 128
#define C2 256   // HEADS*HID
#define NEG 0.2f

typedef __bf16 v8bf __attribute__((ext_vector_type(8)));
typedef float  v4f  __attribute__((ext_vector_type(4)));
typedef unsigned short us8 __attribute__((ext_vector_type(8)));

__device__ __forceinline__ float bf2f(unsigned short u) {
    union { float f; unsigned int i; } v; v.i = ((unsigned int)u) << 16; return v.f;
}
__device__ __forceinline__ unsigned short f2bf(float f) {
    union { float f; unsigned int i; } v; v.f = f;
    unsigned int r = v.i + 0x7FFFu + ((v.i >> 16) & 1u);
    return (unsigned short)(r >> 16);
}
__device__ __forceinline__ float lrelu(float x) { return x > 0.f ? x : NEG * x; }

// ---------------- fp32 W[K,N] -> bf16 Wt[N,K] transpose staging ----------------
__global__ __launch_bounds__(256) void cvtT_bf16(const float* __restrict__ src,
                                                 unsigned short* __restrict__ dst,
                                                 int K, int N) {
    int i = blockIdx.x * 256 + threadIdx.x;
    if (i >= K * N) return;
    int k = i / N, n = i - k * N;
    dst[(size_t)n * K + k] = f2bf(src[i]);
}

// ---------------- CSR build ----------------
__global__ void zero_int(int* p, int n) {
    int i = blockIdx.x * 256 + threadIdx.x;
    if (i < n) p[i] = 0;
}

__global__ void hist_kernel(const int* __restrict__ ei, int* __restrict__ cnt, int E, int N) {
    int i = blockIdx.x * 256 + threadIdx.x;
    if (i >= E + N) return;
    int d = (i < E) ? ei[E + i] : (i - E);
    atomicAdd(&cnt[d], 1);
}

__global__ __launch_bounds__(256) void scanA(const int* __restrict__ cnt, int* __restrict__ rs,
                                             int* __restrict__ part, int N) {
    __shared__ int s[256];
    int t = threadIdx.x, i = blockIdx.x * 256 + t;
    int v = (i < N) ? cnt[i] : 0;
    s[t] = v; __syncthreads();
    for (int off = 1; off < 256; off <<= 1) {
        int x = (t >= off) ? s[t - off] : 0;
        __syncthreads();
        s[t] += x;
        __syncthreads();
    }
    if (i < N) rs[i] = s[t] - v;
    if (t == 255) part[blockIdx.x] = s[255];
}

__global__ __launch_bounds__(256) void scanB(int* __restrict__ part, int n) {
    __shared__ int s[256];
    int t = threadIdx.x;
    int v = (t < n) ? part[t] : 0;
    s[t] = v; __syncthreads();
    for (int off = 1; off < 256; off <<= 1) {
        int x = (t >= off) ? s[t - off] : 0;
        __syncthreads();
        s[t] += x;
        __syncthreads();
    }
    if (t < n) part[t] = s[t] - v;
}

__global__ void scanC(int* __restrict__ rs, const int* __restrict__ part,
                      int* __restrict__ cur, int N, int ET) {
    int i = blockIdx.x * 256 + threadIdx.x;
    if (i < N) {
        int v = rs[i] + part[blockIdx.x];
        rs[i] = v;
        cur[i] = v;
    }
    if (i == 0) rs[N] = ET;
}

__global__ void scatter_kernel(const int* __restrict__ ei, int* __restrict__ cur,
                               int* __restrict__ csr, int E, int N) {
    int i = blockIdx.x * 256 + threadIdx.x;
    if (i >= E + N) return;
    int s, d;
    if (i < E) { s = ei[i]; d = ei[E + i]; } else { s = d = i - E; }
    int pos = atomicAdd(&cur[d], 1);
    csr[pos] = s;
}

// ---------------- GEMM (layers 1,2): C[M,N] = A @ Bt^T, fused alpha dots ----------------
// wave = 16 rows x 128 cols (one full head g); writes h (bf16) and asd dots directly.
// mfma layout: A[m=l16][k=quad*8+j], B[k=quad*8+j][n=l16], D col=l16,row=quad*4+r
template<bool AFP32>
__global__ __launch_bounds__(256) void gemm_alpha(const void* __restrict__ Av,
                                                  const unsigned short* __restrict__ Bt,
                                                  const float* __restrict__ asrc,
                                                  const float* __restrict__ adst,
                                                  float* __restrict__ asd,
                                                  unsigned short* __restrict__ C,
                                                  int M, int N, int K) {
    int ngrp = N >> 7;
    int w = (blockIdx.x << 2) + (threadIdx.x >> 6);
    int mt = w / ngrp, g = w - mt * ngrp;
    if (mt * 16 >= M) return;
    int lane = threadIdx.x & 63;
    int l16 = lane & 15, quad = lane >> 4;
    int n0 = g << 7;
    const unsigned short* Bp = Bt + (size_t)(n0 + l16) * K + quad * 8;
    v4f acc[8];
#pragma unroll
    for (int t = 0; t < 8; ++t) acc[t] = (v4f){0.f, 0.f, 0.f, 0.f};

    if (AFP32) {
        const float* Ap = (const float*)Av + (size_t)(mt * 16 + l16) * K + quad * 8;
        for (int k0 = 0; k0 < K; k0 += 32) {
            float4 a0 = *(const float4*)(Ap + k0);
            float4 a1 = *(const float4*)(Ap + k0 + 4);
            v8bf af;
            af[0] = (__bf16)a0.x; af[1] = (__bf16)a0.y; af[2] = (__bf16)a0.z; af[3] = (__bf16)a0.w;
            af[4] = (__bf16)a1.x; af[5] = (__bf16)a1.y; af[6] = (__bf16)a1.z; af[7] = (__bf16)a1.w;
#pragma unroll
            for (int t = 0; t < 8; ++t) {
                v8bf bfr = *(const v8bf*)(Bp + (size_t)t * 16 * K + k0);
                acc[t] = __builtin_amdgcn_mfma_f32_16x16x32_bf16(af, bfr, acc[t], 0, 0, 0);
            }
        }
    } else {
        const unsigned short* Ap = (const unsigned short*)Av + (size_t)(mt * 16 + l16) * K + quad * 8;
        for (int k0 = 0; k0 < K; k0 += 32) {
            v8bf af = *(const v8bf*)(Ap + k0);
#pragma unroll
            for (int t = 0; t < 8; ++t) {
                v8bf bfr = *(const v8bf*)(Bp + (size_t)t * 16 * K + k0);
                acc[t] = __builtin_amdgcn_mfma_f32_16x16x32_bf16(af, bfr, acc[t], 0, 0, 0);
            }
        }
    }

    // store h (bf16, round-to-nearest) and compute alpha dots from the ROUNDED values
    // (matches what agg/alpha would read back)
    int row0 = mt * 16 + quad * 4;
    float sv[8], dv[8];
#pragma unroll
    for (int t = 0; t < 8; ++t) {
        int col = n0 + t * 16 + l16;
        sv[t] = asrc[col];
        dv[t] = adst[col];
    }
#pragma unroll
    for (int r = 0; r < 4; ++r) {
        float sa = 0.f, sd = 0.f;
#pragma unroll
        for (int t = 0; t < 8; ++t) {
            int col = n0 + t * 16 + l16;
            unsigned short hb = f2bf(acc[t][r]);
            C[(size_t)(row0 + r) * N + col] = hb;
            float hv = bf2f(hb);
            sa += hv * sv[t];
            sd += hv * dv[t];
        }
#pragma unroll
        for (int off = 8; off; off >>= 1) {
            sa += __shfl_xor(sa, off);
            sd += __shfl_xor(sd, off);
        }
        if (l16 == 0) {
            int row = row0 + r;
            asd[(size_t)row * 4 + g]     = sa;
            asd[(size_t)row * 4 + 2 + g] = sd;
        }
    }
}

// ---------------- single-pass per-destination softmax+aggregate; one wave per dest ----------------
// no max-subtraction: e = lrelu(as+ad) is bounded (|e| < ~30), exp(e) safe in fp32.
// lane = e2*32 + sub; e2 picks edge of pair, sub covers 8 channels (head = sub>>4).
__global__ __launch_bounds__(256) void agg_kernel(const int* __restrict__ rs,
                                                  const int* __restrict__ csr,
                                                  const unsigned short* __restrict__ h,
                                                  const float* __restrict__ asd,
                                                  const float* __restrict__ bias,
                                                  unsigned short* __restrict__ out, int N) {
    int d = blockIdx.x * 4 + (threadIdx.x >> 6);
    if (d >= N) return;
    int lane = threadIdx.x & 63;
    int beg = rs[d], end = rs[d + 1];
    int e2 = lane >> 5;
    int sub = lane & 31;
    int head = sub >> 4;
    float adh = asd[(size_t)d * 4 + 2 + head];
    int cbase = sub * 8;
    float a[8];
#pragma unroll
    for (int j = 0; j < 8; ++j) a[j] = 0.f;
    float den = 0.f;
#pragma unroll 2
    for (int i = beg; i < end; i += 2) {
        int ei = i + e2;
        bool valid = ei < end;
        int s = csr[valid ? ei : end - 1];
        float e = lrelu(asd[(size_t)s * 4 + head] + adh);
        float wgt = valid ? __expf(e) : 0.f;
        den += wgt;
        us8 hv = *(const us8*)(h + (size_t)s * C2 + cbase);
#pragma unroll
        for (int j = 0; j < 8; ++j) a[j] += wgt * bf2f(hv[j]);
    }
#pragma unroll
    for (int j = 0; j < 8; ++j) a[j] += __shfl_xor(a[j], 32);
    den += __shfl_xor(den, 32);
    if (e2 == 0) {
        float rden = 1.f / (den + 1e-16f);
        us8 o;
#pragma unroll
        for (int j = 0; j < 8; ++j) o[j] = f2bf(fmaxf(a[j] * rden + bias[cbase + j], 0.f));
        *(us8*)(out + (size_t)d * C2 + cbase) = o;
    }
}

// ---------------- post-MLP fused: t = A@Wp1t^T + bp1; out = sigmoid(t . Wp2 + bp2) ----------------
// wave = 16 rows x 128 cols = the full t row; no t materialization.
__global__ __launch_bounds__(256) void gemm_final(const unsigned short* __restrict__ A,
                                                  const unsigned short* __restrict__ Bt,
                                                  const float* __restrict__ bp1,
                                                  const float* __restrict__ wp2,
                                                  const float* __restrict__ bp2,
                                                  float* __restrict__ out,
                                                  int M, int K) {
    int mt = (blockIdx.x << 2) + (threadIdx.x >> 6);
    if (mt * 16 >= M) return;
    int lane = threadIdx.x & 63;
    int l16 = lane & 15, quad = lane >> 4;
    const unsigned short* Ap = A + (size_t)(mt * 16 + l16) * K + quad * 8;
    const unsigned short* Bp = Bt + (size_t)l16 * K + quad * 8;
    v4f acc[8];
#pragma unroll
    for (int t = 0; t < 8; ++t) acc[t] = (v4f){0.f, 0.f, 0.f, 0.f};
    for (int k0 = 0; k0 < K; k0 += 32) {
        v8bf af = *(const v8bf*)(Ap + k0);
#pragma unroll
        for (int t = 0; t < 8; ++t) {
            v8bf bfr = *(const v8bf*)(Bp + (size_t)t * 16 * K + k0);
            acc[t] = __builtin_amdgcn_mfma_f32_16x16x32_bf16(af, bfr, acc[t], 0, 0, 0);
        }
    }
    float wv[8], bv[8];
#pragma unroll
    for (int t = 0; t < 8; ++t) {
        int col = t * 16 + l16;
        wv[t] = wp2[col];
        bv[t] = bp1[col];
    }
    float bias2 = bp2[0];
    int row0 = mt * 16 + quad * 4;
#pragma unroll
    for (int r = 0; r < 4; ++r) {
        float s = 0.f;
#pragma unroll
        for (int t = 0; t < 8; ++t) s += (acc[t][r] + bv[t]) * wv[t];
#pragma unroll
        for (int off = 8; off; off >>= 1) s += __shfl_xor(s, off);
        if (l16 == 0) {
            float x = s + bias2;
            out[row0 + r] = 1.f / (1.f + __expf(-x));
        }
    }
}

extern "C" void kernel_launch(void* const* d_in, const int* in_sizes, int n_in,
                              void* d_out, int out_size, void* d_ws, size_t ws_size,
                              hipStream_t stream) {
    const float* x   = (const float*)d_in[0];
    const int*   ei  = (const int*)d_in[1];
    const float* W1  = (const float*)d_in[2];
    const float* as1 = (const float*)d_in[3];
    const float* ad1 = (const float*)d_in[4];
    const float* b1  = (const float*)d_in[5];
    const float* W2  = (const float*)d_in[6];
    const float* as2 = (const float*)d_in[7];
    const float* ad2 = (const float*)d_in[8];
    const float* b2  = (const float*)d_in[9];
    const float* Wp1 = (const float*)d_in[10];
    const float* bp1 = (const float*)d_in[11];
    const float* Wp2 = (const float*)d_in[12];
    const float* bp2 = (const float*)d_in[13];
    float* out = (float*)d_out;

    int NN = in_sizes[0] / HID;   // 50000
    int E  = in_sizes[1] / 2;     // 800000
    int ET = E + NN;

    char* ws = (char*)d_ws;
    size_t off = 0;
    auto alloc = [&](size_t bytes) -> char* {
        char* p = ws + off;
        off += (bytes + 255) & ~(size_t)255;
        return p;
    };
    unsigned short* bufH = (unsigned short*)alloc((size_t)NN * C2 * 2);
    unsigned short* bufO = (unsigned short*)alloc((size_t)NN * C2 * 2);
    float* asd = (float*)alloc((size_t)NN * 4 * sizeof(float));
    int* rs    = (int*)alloc((size_t)(NN + 1) * 4);
    int* cur   = (int*)alloc((size_t)NN * 4);
    int* csr   = (int*)alloc((size_t)ET * 4);
    int* part  = (int*)alloc(1024);
    unsigned short* W1t  = (unsigned short*)alloc((size_t)HID * C2 * 2);  // [256,128]
    unsigned short* W2t  = (unsigned short*)alloc((size_t)C2 * C2 * 2);   // [256,256]
    unsigned short* Wp1t = (unsigned short*)alloc((size_t)C2 * HID * 2);  // [128,256]

    int nchunk = (NN + 255) / 256;
    int eblk   = (ET + 255) / 256;

    // weight staging (transpose + bf16)
    cvtT_bf16<<<(HID * C2 + 255) / 256, 256, 0, stream>>>(W1, W1t, HID, C2);
    cvtT_bf16<<<(C2 * C2 + 255) / 256, 256, 0, stream>>>(W2, W2t, C2, C2);
    cvtT_bf16<<<(C2 * HID + 255) / 256, 256, 0, stream>>>(Wp1, Wp1t, C2, HID);

    // CSR build
    zero_int<<<nchunk, 256, 0, stream>>>(cur, NN);
    hist_kernel<<<eblk, 256, 0, stream>>>(ei, cur, E, NN);
    scanA<<<nchunk, 256, 0, stream>>>(cur, rs, part, NN);
    scanB<<<1, 256, 0, stream>>>(part, nchunk);
    scanC<<<nchunk, 256, 0, stream>>>(rs, part, cur, NN, ET);
    scatter_kernel<<<eblk, 256, 0, stream>>>(ei, cur, csr, E, NN);

    int mt = NN / 16;                       // 3125 m-tiles
    int w256 = mt * 2;                      // 16x128 strips over N=256

    // layer 1 (A = fp32 x, cvt in-register) + fused alpha dots
    gemm_alpha<true><<<(w256 + 3) / 4, 256, 0, stream>>>(x, W1t, as1, ad1, asd, bufH, NN, C2, HID);
    agg_kernel<<<(NN + 3) / 4, 256, 0, stream>>>(rs, csr, bufH, asd, b1, bufO, NN);
    // layer 2
    gemm_alpha<false><<<(w256 + 3) / 4, 256, 0, stream>>>(bufO, W2t, as2, ad2, asd, bufH, NN, C2, C2);
    agg_kernel<<<(NN + 3) / 4, 256, 0, stream>>>(rs, csr, bufH, asd, b2, bufO, NN);
    // post-MLP fully fused
    gemm_final<<<(mt + 3) / 4, 256, 0, stream>>>(bufO, Wp1t, bp1, Wp2, bp2, out, NN, C2);
}

// Round 5
// 381.430 us; speedup vs baseline: 1.6883x; 1.1810x over previous
//
#include <hip/hip_runtime.h>

#define HID 128
#define C2 256   // HEADS*HID
#define NEG 0.2f

typedef __bf16 v8bf __attribute__((ext_vector_type(8)));
typedef float  v4f  __attribute__((ext_vector_type(4)));
typedef unsigned short us8 __attribute__((ext_vector_type(8)));

__device__ __forceinline__ float bf2f(unsigned short u) {
    union { float f; unsigned int i; } v; v.i = ((unsigned int)u) << 16; return v.f;
}
__device__ __forceinline__ unsigned short f2bf(float f) {
    union { float f; unsigned int i; } v; v.f = f;
    unsigned int r = v.i + 0x7FFFu + ((v.i >> 16) & 1u);
    return (unsigned short)(r >> 16);
}
__device__ __forceinline__ float lrelu(float x) { return x > 0.f ? x : NEG * x; }

// ---------------- pack W[K,N] fp32 -> bf16 MFMA-B-fragment order ----------------
// Bpack element j of flat frag idx = ((nt*ksteps + k0)*64 + lane):
//   W[k0*32 + (lane>>4)*8 + j][nt*16 + (lane&15)]
// In the GEMM, a wave's B-frag load is then base + lane*16B — fully coalesced.
__global__ __launch_bounds__(256) void packB(const float* __restrict__ W,
                                             unsigned short* __restrict__ out,
                                             int K, int N) {
    int idx = blockIdx.x * 256 + threadIdx.x;
    int ksteps = K >> 5;
    int total = (N >> 4) * ksteps * 64;
    if (idx >= total) return;
    int lane = idx & 63;
    int rest = idx >> 6;
    int nt = rest / ksteps, k0 = rest - nt * ksteps;
    int n = nt * 16 + (lane & 15);
    int kb = k0 * 32 + (lane >> 4) * 8;
    us8 v;
#pragma unroll
    for (int j = 0; j < 8; ++j) v[j] = f2bf(W[(size_t)(kb + j) * N + n]);
    *(us8*)(out + (size_t)idx * 8) = v;
}

// ---------------- CSR build ----------------
__global__ void zero_int(int* p, int n) {
    int i = blockIdx.x * 256 + threadIdx.x;
    if (i < n) p[i] = 0;
}

__global__ void hist_kernel(const int* __restrict__ ei, int* __restrict__ cnt, int E, int N) {
    int i = blockIdx.x * 256 + threadIdx.x;
    if (i >= E + N) return;
    int d = (i < E) ? ei[E + i] : (i - E);
    atomicAdd(&cnt[d], 1);
}

__global__ __launch_bounds__(256) void scanA(const int* __restrict__ cnt, int* __restrict__ rs,
                                             int* __restrict__ part, int N) {
    __shared__ int s[256];
    int t = threadIdx.x, i = blockIdx.x * 256 + t;
    int v = (i < N) ? cnt[i] : 0;
    s[t] = v; __syncthreads();
    for (int off = 1; off < 256; off <<= 1) {
        int x = (t >= off) ? s[t - off] : 0;
        __syncthreads();
        s[t] += x;
        __syncthreads();
    }
    if (i < N) rs[i] = s[t] - v;
    if (t == 255) part[blockIdx.x] = s[255];
}

__global__ __launch_bounds__(256) void scanB(int* __restrict__ part, int n) {
    __shared__ int s[256];
    int t = threadIdx.x;
    int v = (t < n) ? part[t] : 0;
    s[t] = v; __syncthreads();
    for (int off = 1; off < 256; off <<= 1) {
        int x = (t >= off) ? s[t - off] : 0;
        __syncthreads();
        s[t] += x;
        __syncthreads();
    }
    if (t < n) part[t] = s[t] - v;
}

__global__ void scanC(int* __restrict__ rs, const int* __restrict__ part,
                      int* __restrict__ cur, int N, int ET) {
    int i = blockIdx.x * 256 + threadIdx.x;
    if (i < N) {
        int v = rs[i] + part[blockIdx.x];
        rs[i] = v;
        cur[i] = v;
    }
    if (i == 0) rs[N] = ET;
}

__global__ void scatter_kernel(const int* __restrict__ ei, int* __restrict__ cur,
                               int* __restrict__ csr, int E, int N) {
    int i = blockIdx.x * 256 + threadIdx.x;
    if (i >= E + N) return;
    int s, d;
    if (i < E) { s = ei[i]; d = ei[E + i]; } else { s = d = i - E; }
    int pos = atomicAdd(&cur[d], 1);
    csr[pos] = s;
}

// ---------------- GEMM (layers 1,2): fused alpha dots; 2 m-tiles per wave ----------------
// wave = 32 rows x 128 cols (one head g). B from packed fragments (coalesced).
// mfma layout: A[m=l16][k=quad*8+j], D col=l16,row=quad*4+r
template<bool AFP32>
__global__ __launch_bounds__(256) void gemm_alpha(const void* __restrict__ Av,
                                                  const unsigned short* __restrict__ Bp,
                                                  const float* __restrict__ asrc,
                                                  const float* __restrict__ adst,
                                                  float* __restrict__ asd,
                                                  unsigned short* __restrict__ C,
                                                  int M, int N, int K) {
    int ksteps = K >> 5;
    int ngrp = N >> 7;
    int mtiles = M >> 4;
    int pairs = (mtiles + 1) >> 1;
    int w = (blockIdx.x << 2) + (threadIdx.x >> 6);
    int mp = w / ngrp, g = w - mp * ngrp;
    if (mp >= pairs) return;
    int mt0 = mp * 2, mt1 = mt0 + 1;
    bool has1 = mt1 < mtiles;
    int mt1s = has1 ? mt1 : mt0;
    int lane = threadIdx.x & 63;
    int l16 = lane & 15, quad = lane >> 4;

    const unsigned short* Bf = Bp + ((size_t)(g * 8) * ksteps << 9) + lane * 8;
    v4f acc0[8], acc1[8];
#pragma unroll
    for (int t = 0; t < 8; ++t) { acc0[t] = (v4f){0,0,0,0}; acc1[t] = (v4f){0,0,0,0}; }

    for (int k0 = 0; k0 < ksteps; ++k0) {
        v8bf a0, a1;
        if (AFP32) {
            const float* A = (const float*)Av;
            const float* p0 = A + (size_t)(mt0 * 16 + l16) * K + k0 * 32 + quad * 8;
            const float* p1 = A + (size_t)(mt1s * 16 + l16) * K + k0 * 32 + quad * 8;
            float4 u0 = *(const float4*)p0, u1 = *(const float4*)(p0 + 4);
            float4 v0 = *(const float4*)p1, v1 = *(const float4*)(p1 + 4);
            a0[0]=(__bf16)u0.x; a0[1]=(__bf16)u0.y; a0[2]=(__bf16)u0.z; a0[3]=(__bf16)u0.w;
            a0[4]=(__bf16)u1.x; a0[5]=(__bf16)u1.y; a0[6]=(__bf16)u1.z; a0[7]=(__bf16)u1.w;
            a1[0]=(__bf16)v0.x; a1[1]=(__bf16)v0.y; a1[2]=(__bf16)v0.z; a1[3]=(__bf16)v0.w;
            a1[4]=(__bf16)v1.x; a1[5]=(__bf16)v1.y; a1[6]=(__bf16)v1.z; a1[7]=(__bf16)v1.w;
        } else {
            const unsigned short* A = (const unsigned short*)Av;
            a0 = *(const v8bf*)(A + (size_t)(mt0 * 16 + l16) * K + k0 * 32 + quad * 8);
            a1 = *(const v8bf*)(A + (size_t)(mt1s * 16 + l16) * K + k0 * 32 + quad * 8);
        }
#pragma unroll
        for (int t = 0; t < 8; ++t) {
            v8bf bfr = *(const v8bf*)(Bf + ((size_t)(t * ksteps + k0) << 9));
            acc0[t] = __builtin_amdgcn_mfma_f32_16x16x32_bf16(a0, bfr, acc0[t], 0, 0, 0);
            acc1[t] = __builtin_amdgcn_mfma_f32_16x16x32_bf16(a1, bfr, acc1[t], 0, 0, 0);
        }
    }

    int n0 = g << 7;
    float sv[8], dv[8];
#pragma unroll
    for (int t = 0; t < 8; ++t) {
        int col = n0 + t * 16 + l16;
        sv[t] = asrc[col];
        dv[t] = adst[col];
    }
    // epilogue per m-tile: store rounded h, alpha dots from rounded values
#pragma unroll
    for (int mi = 0; mi < 2; ++mi) {
        if (mi == 1 && !has1) break;
        v4f* acc = mi ? acc1 : acc0;
        int row0 = (mi ? mt1 : mt0) * 16 + quad * 4;
#pragma unroll
        for (int r = 0; r < 4; ++r) {
            float sa = 0.f, sd = 0.f;
#pragma unroll
            for (int t = 0; t < 8; ++t) {
                int col = n0 + t * 16 + l16;
                unsigned short hb = f2bf(acc[t][r]);
                C[(size_t)(row0 + r) * N + col] = hb;
                float hv = bf2f(hb);
                sa += hv * sv[t];
                sd += hv * dv[t];
            }
#pragma unroll
            for (int off = 8; off; off >>= 1) {
                sa += __shfl_xor(sa, off);
                sd += __shfl_xor(sd, off);
            }
            if (l16 == 0) {
                int row = row0 + r;
                asd[(size_t)row * 4 + g]     = sa;
                asd[(size_t)row * 4 + 2 + g] = sd;
            }
        }
    }
}

// ---------------- single-pass per-destination softmax+aggregate; one wave per dest ----------------
__global__ __launch_bounds__(256) void agg_kernel(const int* __restrict__ rs,
                                                  const int* __restrict__ csr,
                                                  const unsigned short* __restrict__ h,
                                                  const float* __restrict__ asd,
                                                  const float* __restrict__ bias,
                                                  unsigned short* __restrict__ out, int N) {
    int d = blockIdx.x * 4 + (threadIdx.x >> 6);
    if (d >= N) return;
    int lane = threadIdx.x & 63;
    int beg = rs[d], end = rs[d + 1];
    int e2 = lane >> 5;
    int sub = lane & 31;
    int head = sub >> 4;
    float adh = asd[(size_t)d * 4 + 2 + head];
    int cbase = sub * 8;
    float a[8];
#pragma unroll
    for (int j = 0; j < 8; ++j) a[j] = 0.f;
    float den = 0.f;
#pragma unroll 2
    for (int i = beg; i < end; i += 2) {
        int ei = i + e2;
        bool valid = ei < end;
        int s = csr[valid ? ei : end - 1];
        float e = lrelu(asd[(size_t)s * 4 + head] + adh);
        float wgt = valid ? __expf(e) : 0.f;
        den += wgt;
        us8 hv = *(const us8*)(h + (size_t)s * C2 + cbase);
#pragma unroll
        for (int j = 0; j < 8; ++j) a[j] += wgt * bf2f(hv[j]);
    }
#pragma unroll
    for (int j = 0; j < 8; ++j) a[j] += __shfl_xor(a[j], 32);
    den += __shfl_xor(den, 32);
    if (e2 == 0) {
        float rden = 1.f / (den + 1e-16f);
        us8 o;
#pragma unroll
        for (int j = 0; j < 8; ++j) o[j] = f2bf(fmaxf(a[j] * rden + bias[cbase + j], 0.f));
        *(us8*)(out + (size_t)d * C2 + cbase) = o;
    }
}

// ---------------- post-MLP fused: t = A@Wp1 + bp1; out = sigmoid(t.Wp2 + bp2); 2 m-tiles/wave ----------------
__global__ __launch_bounds__(256) void gemm_final(const unsigned short* __restrict__ A,
                                                  const unsigned short* __restrict__ Bp,
                                                  const float* __restrict__ bp1,
                                                  const float* __restrict__ wp2,
                                                  const float* __restrict__ bp2,
                                                  float* __restrict__ out,
                                                  int M, int K) {
    int ksteps = K >> 5;                 // 8
    int mtiles = M >> 4;
    int pairs = (mtiles + 1) >> 1;
    int mp = (blockIdx.x << 2) + (threadIdx.x >> 6);
    if (mp >= pairs) return;
    int mt0 = mp * 2, mt1 = mt0 + 1;
    bool has1 = mt1 < mtiles;
    int mt1s = has1 ? mt1 : mt0;
    int lane = threadIdx.x & 63;
    int l16 = lane & 15, quad = lane >> 4;

    const unsigned short* Bf = Bp + lane * 8;
    v4f acc0[8], acc1[8];
#pragma unroll
    for (int t = 0; t < 8; ++t) { acc0[t] = (v4f){0,0,0,0}; acc1[t] = (v4f){0,0,0,0}; }
    for (int k0 = 0; k0 < ksteps; ++k0) {
        v8bf a0 = *(const v8bf*)(A + (size_t)(mt0 * 16 + l16) * K + k0 * 32 + quad * 8);
        v8bf a1 = *(const v8bf*)(A + (size_t)(mt1s * 16 + l16) * K + k0 * 32 + quad * 8);
#pragma unroll
        for (int t = 0; t < 8; ++t) {
            v8bf bfr = *(const v8bf*)(Bf + ((size_t)(t * ksteps + k0) << 9));
            acc0[t] = __builtin_amdgcn_mfma_f32_16x16x32_bf16(a0, bfr, acc0[t], 0, 0, 0);
            acc1[t] = __builtin_amdgcn_mfma_f32_16x16x32_bf16(a1, bfr, acc1[t], 0, 0, 0);
        }
    }
    float wv[8], bv[8];
#pragma unroll
    for (int t = 0; t < 8; ++t) {
        int col = t * 16 + l16;
        wv[t] = wp2[col];
        bv[t] = bp1[col];
    }
    float bias2 = bp2[0];
#pragma unroll
    for (int mi = 0; mi < 2; ++mi) {
        if (mi == 1 && !has1) break;
        v4f* acc = mi ? acc1 : acc0;
        int row0 = (mi ? mt1 : mt0) * 16 + quad * 4;
#pragma unroll
        for (int r = 0; r < 4; ++r) {
            float s = 0.f;
#pragma unroll
            for (int t = 0; t < 8; ++t) s += (acc[t][r] + bv[t]) * wv[t];
#pragma unroll
            for (int off = 8; off; off >>= 1) s += __shfl_xor(s, off);
            if (l16 == 0) {
                float xv = s + bias2;
                out[row0 + r] = 1.f / (1.f + __expf(-xv));
            }
        }
    }
}

extern "C" void kernel_launch(void* const* d_in, const int* in_sizes, int n_in,
                              void* d_out, int out_size, void* d_ws, size_t ws_size,
                              hipStream_t stream) {
    const float* x   = (const float*)d_in[0];
    const int*   ei  = (const int*)d_in[1];
    const float* W1  = (const float*)d_in[2];
    const float* as1 = (const float*)d_in[3];
    const float* ad1 = (const float*)d_in[4];
    const float* b1  = (const float*)d_in[5];
    const float* W2  = (const float*)d_in[6];
    const float* as2 = (const float*)d_in[7];
    const float* ad2 = (const float*)d_in[8];
    const float* b2  = (const float*)d_in[9];
    const float* Wp1 = (const float*)d_in[10];
    const float* bp1 = (const float*)d_in[11];
    const float* Wp2 = (const float*)d_in[12];
    const float* bp2 = (const float*)d_in[13];
    float* out = (float*)d_out;

    int NN = in_sizes[0] / HID;   // 50000
    int E  = in_sizes[1] / 2;     // 800000
    int ET = E + NN;

    char* ws = (char*)d_ws;
    size_t off = 0;
    auto alloc = [&](size_t bytes) -> char* {
        char* p = ws + off;
        off += (bytes + 255) & ~(size_t)255;
        return p;
    };
    unsigned short* bufH = (unsigned short*)alloc((size_t)NN * C2 * 2);
    unsigned short* bufO = (unsigned short*)alloc((size_t)NN * C2 * 2);
    float* asd = (float*)alloc((size_t)NN * 4 * sizeof(float));
    int* rs    = (int*)alloc((size_t)(NN + 1) * 4);
    int* cur   = (int*)alloc((size_t)NN * 4);
    int* csr   = (int*)alloc((size_t)ET * 4);
    int* part  = (int*)alloc(1024);
    unsigned short* W1p  = (unsigned short*)alloc((size_t)HID * C2 * 2);  // packed
    unsigned short* W2p  = (unsigned short*)alloc((size_t)C2 * C2 * 2);
    unsigned short* Wp1p = (unsigned short*)alloc((size_t)C2 * HID * 2);

    int nchunk = (NN + 255) / 256;
    int eblk   = (ET + 255) / 256;

    // weight staging (bf16 + MFMA-fragment packing)
    packB<<<(HID * C2 / 8 + 255) / 256, 256, 0, stream>>>(W1, W1p, HID, C2);
    packB<<<(C2 * C2 / 8 + 255) / 256, 256, 0, stream>>>(W2, W2p, C2, C2);
    packB<<<(C2 * HID / 8 + 255) / 256, 256, 0, stream>>>(Wp1, Wp1p, C2, HID);

    // CSR build
    zero_int<<<nchunk, 256, 0, stream>>>(cur, NN);
    hist_kernel<<<eblk, 256, 0, stream>>>(ei, cur, E, NN);
    scanA<<<nchunk, 256, 0, stream>>>(cur, rs, part, NN);
    scanB<<<1, 256, 0, stream>>>(part, nchunk);
    scanC<<<nchunk, 256, 0, stream>>>(rs, part, cur, NN, ET);
    scatter_kernel<<<eblk, 256, 0, stream>>>(ei, cur, csr, E, NN);

    int mtiles = NN / 16;                    // 3125
    int pairs = (mtiles + 1) / 2;            // 1563
    int wgemm = pairs * 2;                   // ngrp=2
    // layer 1 (A = fp32 x, cvt in-register) + fused alpha dots
    gemm_alpha<true><<<(wgemm + 3) / 4, 256, 0, stream>>>(x, W1p, as1, ad1, asd, bufH, NN, C2, HID);
    agg_kernel<<<(NN + 3) / 4, 256, 0, stream>>>(rs, csr, bufH, asd, b1, bufO, NN);
    // layer 2
    gemm_alpha<false><<<(wgemm + 3) / 4, 256, 0, stream>>>(bufO, W2p, as2, ad2, asd, bufH, NN, C2, C2);
    agg_kernel<<<(NN + 3) / 4, 256, 0, stream>>>(rs, csr, bufH, asd, b2, bufO, NN);
    // post-MLP fully fused
    gemm_final<<<(pairs + 3) / 4, 256, 0, stream>>>(bufO, Wp1p, bp1, Wp2, bp2, out, NN, C2);
}